// Round 16
// baseline (176.315 us; speedup 1.0000x reference)
//
#include <hip/hip_runtime.h>

#define NB 4
#define SEQ 4096
#define DM 512
#define DA 64
#define LOG2E 1.44269504f

typedef __attribute__((ext_vector_type(8))) short bf16x8;
typedef __attribute__((ext_vector_type(4))) float f32x4;
typedef __attribute__((ext_vector_type(16))) float f32x16;
typedef __attribute__((address_space(3))) unsigned int lds_u32;
typedef const __attribute__((address_space(1))) unsigned int glb_u32;

__device__ __forceinline__ unsigned short f2bf(float f) {
  unsigned u = __float_as_uint(f);
  u += 0x7fffu + ((u >> 16) & 1u);
  return (unsigned short)(u >> 16);
}

__device__ __forceinline__ float bf2f(unsigned short h) {
  return __uint_as_float(((unsigned)h) << 16);
}

__device__ __forceinline__ unsigned cvt_pk_bf16(float lo, float hi) {
  unsigned r;
  asm("v_cvt_pk_bf16_f32 %0, %1, %2" : "=v"(r) : "v"(lo), "v"(hi));
  return r;
}

__device__ __forceinline__ float fexp2(float x) {
  float r;
  asm("v_exp_f32 %0, %1" : "=v"(r) : "v"(x));
  return r;
}

__device__ __forceinline__ void g2lds16(const unsigned short* g, unsigned short* l) {
  __builtin_amdgcn_global_load_lds((glb_u32*)g, (lds_u32*)l, 16, 0, 0);
}

// ------------- Kernel 1: cast x -> bf16  AND  build Wt[640][512] + bias (merged) -----
__global__ void prep_kernel(const float* __restrict__ x, unsigned short* __restrict__ xb,
                            const float* __restrict__ Wq, const float* __restrict__ bq,
                            const float* __restrict__ Wk, const float* __restrict__ bk,
                            const float* __restrict__ Wv, const float* __restrict__ bv,
                            unsigned short* __restrict__ Wt, float* __restrict__ bias) {
  int bid = blockIdx.x;
  if (bid < 8192) {
    size_t i = ((size_t)bid * blockDim.x + threadIdx.x) * 4;
    float4 v = *(const float4*)(x + i);
    ushort4 o;
    o.x = f2bf(v.x); o.y = f2bf(v.y); o.z = f2bf(v.z); o.w = f2bf(v.w);
    *(ushort4*)(xb + i) = o;
  } else {
    int n = bid - 8192;  // 0..639
    for (int k = threadIdx.x; k < DM; k += blockDim.x) {
      float w;
      if (n < 64)       w = Wq[(size_t)k * DA + n];
      else if (n < 128) w = Wk[(size_t)k * DA + (n - 64)];
      else              w = Wv[(size_t)k * DM + (n - 128)];
      Wt[(size_t)n * DM + k] = f2bf(w);
    }
    if (threadIdx.x == 0)
      bias[n] = (n < 64) ? bq[n] : (n < 128) ? bk[n - 64] : bv[n - 128];
  }
}

// ------------- Kernel 2: projection GEMM, 128x128 tile, single-buffered LDS ----------
__launch_bounds__(256)
__global__ void proj_kernel(const unsigned short* __restrict__ xb,
                            const unsigned short* __restrict__ Wt,
                            const float* __restrict__ bias,
                            unsigned short* __restrict__ qws,
                            unsigned short* __restrict__ kp,
                            unsigned short* __restrict__ vp) {
  int C0 = blockIdx.x * 128;     // 0..512
  int R0 = blockIdx.y * 128;     // 0..16256
  int tid = threadIdx.x;
  int w = tid >> 6, lane = tid & 63;
  int g = (lane >> 4) & 3, c15 = lane & 15;
  int wr = w >> 1, wc = w & 1;

  __shared__ unsigned short smem[18432];   // A[8192] | B[8192] | epilogue overlap
  unsigned short* Ab = smem;
  unsigned short* Bb = smem + 8192;

  int row0 = tid >> 3;                     // 0..31
  int scol = (tid & 7) ^ (row0 & 7);       // pre-swizzled source slot
  const unsigned short* srcA = xb + (size_t)(R0 + row0) * DM + scol * 8;
  const unsigned short* srcB = Wt + (size_t)(C0 + row0) * DM + scol * 8;

  auto stage = [&](int kk) {
    for (int r = 0; r < 4; r++)
      g2lds16(srcA + (size_t)(r * 32) * DM + kk, &Ab[(r * 32 + w * 8) * 64]);
    for (int r = 0; r < 4; r++)
      g2lds16(srcB + (size_t)(r * 32) * DM + kk, &Bb[(r * 32 + w * 8) * 64]);
  };

  f32x4 acc[4][4];
#pragma unroll
  for (int i = 0; i < 4; i++)
#pragma unroll
    for (int j = 0; j < 4; j++) acc[i][j] = (f32x4)0.0f;

  stage(0);
  for (int s = 0; s < 8; s++) {
    __syncthreads();   // drain staging (vmcnt) before LDS reads
#pragma unroll
    for (int kc = 0; kc < 2; kc++) {
      bf16x8 a[4], bb2[4];
#pragma unroll
      for (int i = 0; i < 4; i++) {
        int row = wr * 64 + i * 16 + c15;
        a[i] = *(const bf16x8*)&Ab[row * 64 + (((kc << 2) | g) ^ (row & 7)) * 8];
      }
#pragma unroll
      for (int j = 0; j < 4; j++) {
        int row = wc * 64 + j * 16 + c15;
        bb2[j] = *(const bf16x8*)&Bb[row * 64 + (((kc << 2) | g) ^ (row & 7)) * 8];
      }
#pragma unroll
      for (int i = 0; i < 4; i++)
#pragma unroll
        for (int j = 0; j < 4; j++)
          acc[i][j] = __builtin_amdgcn_mfma_f32_16x16x32_bf16(a[i], bb2[j], acc[i][j], 0, 0, 0);
    }
    if (s < 7) {
      __syncthreads();   // all reads done before overwrite
      stage((s + 1) * 64);
    }
  }
  __syncthreads();       // protect epilogue smem reuse

  // ---- epilogue: per-wave 64x64 tile -> LDS [64][72] -> repacked coalesced stores ----
  unsigned short* tw = smem + w * 4608;
  int n0 = C0 + wc * 64;
#pragma unroll
  for (int j = 0; j < 4; j++) {
    int ncol = n0 + j * 16 + c15;
    float bv_ = bias[ncol];
    float qs = (ncol < 64) ? LOG2E : 1.0f;
#pragma unroll
    for (int i = 0; i < 4; i++)
#pragma unroll
      for (int r = 0; r < 4; r++) {
        int sl = i * 16 + g * 4 + r;
        tw[sl * 72 + j * 16 + c15] = f2bf((acc[i][j][r] + bv_) * qs);
      }
  }
  // wave-private region: compiler-inserted lgkmcnt orders write->read within the wave

  int RR = R0 + wr * 64;
  int b = RR >> 12, ktc = (RR & (SEQ - 1)) >> 6;
  if (n0 == 0) {
    for (int it = 0; it < 8; it++) {
      int rid = it * 64 + lane;
      int sl = rid >> 3, grp = rid & 7;
      bf16x8 vd = *(const bf16x8*)&tw[sl * 72 + grp * 8];
      *(bf16x8*)(qws + (size_t)(RR + sl) * DA + grp * 8) = vd;
    }
  } else if (n0 == 64) {
    for (int slot = 0; slot < 8; slot++) {
      bf16x8 vd = *(const bf16x8*)&tw[lane * 72 + slot * 8];
      *(bf16x8*)(kp + ((((size_t)b * 64 + ktc) * 8 + slot) * 64 + lane) * 8) = vd;
    }
  } else {
    int dvbase = n0 - 128;
    int dv = dvbase + lane;
    int dvc2 = dv >> 7, dvrow = dv & 127;
    for (int slot = 0; slot < 8; slot++) {
      union { unsigned short u[8]; bf16x8 h8; } pk;
#pragma unroll
      for (int j = 0; j < 8; j++) {
        int key = ((slot >> 2) << 5) | (((slot >> 1) & 1) << 4) | ((j >> 2) << 3) |
                  ((slot & 1) << 2) | (j & 3);
        pk.u[j] = tw[key * 72 + lane];
      }
      *(bf16x8*)(vp + (((((size_t)(b * 4 + dvc2)) * 64 + ktc) * 8 + slot) * 128 + dvrow) * 8) = pk.h8;
    }
  }
}

// ------------- Kernel 3: fused causal flash attention + residual + LayerNorm ---------
// Grid (4,128): x=b, y->strip (pairing: y<64 ? y : 191-y). Block 256 = 4 waves = the
// 4 dvc chunks of ONE 32-row strip, walking kt in lockstep (raw s_barrier/iter):
// identical K-frag addresses across waves -> L1/MSHR dedup -> K L2-traffic / 4.
// No split-K merge. Epilogue: o=acc/l -> LDS transpose -> per-row LayerNorm with
// residual from xb -> f32 out. launch_bounds(256,3): loop needs ~148 regs (R14:
// requesting 4 waves/SIMD spills acc -> 2.5x slower).
__launch_bounds__(256, 3)
__global__ void attn_ln_kernel(const unsigned short* __restrict__ qws,
                               const unsigned short* __restrict__ kp,
                               const unsigned short* __restrict__ vp,
                               const unsigned short* __restrict__ xb,
                               const float* __restrict__ gamma,
                               const float* __restrict__ beta,
                               float* __restrict__ out) {
  int b = blockIdx.x;
  int yy = blockIdx.y;
  int strip = (yy < 64) ? yy : 191 - yy;   // CU pair (y, y+64) sums to ~const work
  int qrow32 = strip * 32;
  int n = (strip >> 1) + 1;
  int tid = threadIdx.x, w = tid >> 6, lane = tid & 63;
  int l31 = lane & 31, lh = lane >> 5;

  __shared__ unsigned short obuf[32 * 516];   // 33KB; row stride 516 ush (129 words, cf-free)

  size_t bS = (size_t)b * SEQ;

  bf16x8 qf[4];
#pragma unroll
  for (int c = 0; c < 4; c++)
    qf[c] = *(const bf16x8*)(qws + (bS + qrow32 + l31) * DA + c * 16 + lh * 8);

  const unsigned short* kbase = kp + (size_t)b * 64 * 4096 + lh * 512 + l31 * 8;
  const unsigned short* vbase = vp + (size_t)(b * 4 + w) * 64 * 8192 + lh * 1024 + l31 * 8;

  f32x16 acc[4];
#pragma unroll
  for (int dt = 0; dt < 4; dt++) acc[dt] = (f32x16)0.0f;
  float la0 = 0.0f, la1 = 0.0f, la2 = 0.0f, la3 = 0.0f;

  for (int t = 0; t < n; t++) {
    __builtin_amdgcn_s_barrier();   // keep 4 waves phase-aligned for K L1 dedup
    const unsigned short* kt_ = kbase + (size_t)t * 4096;
    const unsigned short* vt_ = vbase + (size_t)t * 8192;

    bf16x8 kf[4][2];
#pragma unroll
    for (int c = 0; c < 4; c++)
#pragma unroll
      for (int s2 = 0; s2 < 2; s2++)
        kf[c][s2] = *(const bf16x8*)(kt_ + c * 1024 + s2 * 256);
    bf16x8 vbA[4];
#pragma unroll
    for (int dt = 0; dt < 4; dt++)
      vbA[dt] = *(const bf16x8*)(vt_ + dt * 256);

    f32x16 sc[2];
    sc[0] = (f32x16)0.0f; sc[1] = (f32x16)0.0f;
    __builtin_amdgcn_s_setprio(1);
#pragma unroll
    for (int c = 0; c < 4; c++)
#pragma unroll
      for (int s2 = 0; s2 < 2; s2++)
        sc[s2] = __builtin_amdgcn_mfma_f32_32x32x16_bf16(kf[c][s2], qf[c], sc[s2], 0, 0, 0);
    __builtin_amdgcn_s_setprio(0);

    if (t == n - 1) {   // diagonal tile only (wave-uniform; same n for all waves)
      int kt = t * 64, qrow = qrow32 + l31;
#pragma unroll
      for (int s2 = 0; s2 < 2; s2++)
#pragma unroll
        for (int p = 0; p < 16; p++) {
          int key = kt + s2 * 32 + (p & 3) + 8 * (p >> 2) + 4 * lh;
          if (key > qrow) sc[s2][p] = -1e30f;
        }
    }

    // ---- P = exp2(S) directly (no max tracking; shift-invariance) ----
#pragma unroll
    for (int s2 = 0; s2 < 2; s2++)
#pragma unroll
      for (int p = 0; p < 16; p += 4) {
        float p0 = fexp2(sc[s2][p + 0]);
        float p1 = fexp2(sc[s2][p + 1]);
        float p2 = fexp2(sc[s2][p + 2]);
        float p3 = fexp2(sc[s2][p + 3]);
        sc[s2][p + 0] = p0; sc[s2][p + 1] = p1;
        sc[s2][p + 2] = p2; sc[s2][p + 3] = p3;
        la0 += p0; la1 += p1; la2 += p2; la3 += p3;
      }

    bf16x8 pa[4];
#pragma unroll
    for (int c = 0; c < 4; c++) {
      union { unsigned u[4]; bf16x8 h; } pu;
      int s2 = c >> 1, o = (c & 1) * 8;
      pu.u[0] = cvt_pk_bf16(sc[s2][o + 0], sc[s2][o + 1]);
      pu.u[1] = cvt_pk_bf16(sc[s2][o + 2], sc[s2][o + 3]);
      pu.u[2] = cvt_pk_bf16(sc[s2][o + 4], sc[s2][o + 5]);
      pu.u[3] = cvt_pk_bf16(sc[s2][o + 6], sc[s2][o + 7]);
      pa[c] = pu.h;
    }

    __builtin_amdgcn_s_setprio(1);
#pragma unroll
    for (int c = 0; c < 4; c++) {
      bf16x8 vbB[4];
      if (c < 3) {
#pragma unroll
        for (int dt = 0; dt < 4; dt++)
          vbB[dt] = *(const bf16x8*)(vt_ + (c + 1) * 2048 + dt * 256);
      }
#pragma unroll
      for (int dt = 0; dt < 4; dt++)
        acc[dt] = __builtin_amdgcn_mfma_f32_32x32x16_bf16(vbA[dt], pa[c], acc[dt], 0, 0, 0);
      if (c < 3) {
#pragma unroll
        for (int dt = 0; dt < 4; dt++) vbA[dt] = vbB[dt];
      }
    }
    __builtin_amdgcn_s_setprio(0);
  }

  // ---- epilogue: o = acc/l -> LDS transpose -> residual + LayerNorm -> f32 out ----
  float l_run = (la0 + la1) + (la2 + la3);
  l_run += __shfl_xor(l_run, 32);
  float inv = 1.0f / l_run;

  unsigned* ob32 = (unsigned*)obuf;
#pragma unroll
  for (int dt = 0; dt < 4; dt++)
#pragma unroll
    for (int p = 0; p < 16; p += 2) {
      int dvl = dt * 32 + (p & 3) + 8 * (p >> 2) + 4 * lh;   // even, 0..127
      ob32[l31 * 258 + w * 64 + (dvl >> 1)] =
          cvt_pk_bf16(acc[dt][p] * inv, acc[dt][p + 1] * inv);
    }
  __syncthreads();

  // per-row LN: wave w handles rows w*8 .. w*8+7; full wave per row
  float4 gv0 = *(const float4*)(gamma + lane * 8);
  float4 gv1 = *(const float4*)(gamma + lane * 8 + 4);
  float4 bv0 = *(const float4*)(beta + lane * 8);
  float4 bv1 = *(const float4*)(beta + lane * 8 + 4);
#pragma unroll
  for (int r = 0; r < 8; r++) {
    int row = w * 8 + r;
    bf16x8 o8 = *(const bf16x8*)&obuf[row * 516 + lane * 8];
    bf16x8 x8 = *(const bf16x8*)(xb + (bS + qrow32 + row) * DM + lane * 8);
    float y[8];
#pragma unroll
    for (int j = 0; j < 8; j++)
      y[j] = bf2f((unsigned short)x8[j]) + bf2f((unsigned short)o8[j]);
    float s1 = 0.0f, s2 = 0.0f;
#pragma unroll
    for (int j = 0; j < 8; j++) { s1 += y[j]; s2 += y[j] * y[j]; }
    for (int m = 1; m < 64; m <<= 1) { s1 += __shfl_xor(s1, m); s2 += __shfl_xor(s2, m); }
    float mu = s1 * (1.0f / DM);
    float var = s2 * (1.0f / DM) - mu * mu;
    float rs = rsqrtf(var + 1e-5f);
    float4 o0, o1;
    o0.x = (y[0] - mu) * rs * gv0.x + bv0.x;
    o0.y = (y[1] - mu) * rs * gv0.y + bv0.y;
    o0.z = (y[2] - mu) * rs * gv0.z + bv0.z;
    o0.w = (y[3] - mu) * rs * gv0.w + bv0.w;
    o1.x = (y[4] - mu) * rs * gv1.x + bv1.x;
    o1.y = (y[5] - mu) * rs * gv1.y + bv1.y;
    o1.z = (y[6] - mu) * rs * gv1.z + bv1.z;
    o1.w = (y[7] - mu) * rs * gv1.w + bv1.w;
    float* dst = out + (bS + qrow32 + row) * DM + lane * 8;
    *(float4*)dst = o0;
    *(float4*)(dst + 4) = o1;
  }
}

extern "C" void kernel_launch(void* const* d_in, const int* in_sizes, int n_in,
                              void* d_out, int out_size, void* d_ws, size_t ws_size,
                              hipStream_t stream) {
  const float* x     = (const float*)d_in[0];
  const float* Wq    = (const float*)d_in[1];
  const float* bq    = (const float*)d_in[2];
  const float* Wk    = (const float*)d_in[3];
  const float* bk    = (const float*)d_in[4];
  const float* Wv    = (const float*)d_in[5];
  const float* bv    = (const float*)d_in[6];
  const float* gamma = (const float*)d_in[7];
  const float* beta  = (const float*)d_in[8];
  float* out = (float*)d_out;

  char* ws = (char*)d_ws;
  unsigned short* xb   = (unsigned short*)(ws + 0);          // 16MB (alive through fused LN)
  unsigned short* qws  = (unsigned short*)(ws + 16777216);   // 2MB
  unsigned short* kp   = (unsigned short*)(ws + 18874368);   // 2MB
  unsigned short* vp   = (unsigned short*)(ws + 20971520);   // 16.78MB
  unsigned short* Wt   = (unsigned short*)(ws + 37748736);   // 0.66MB
  float*          bias = (float*)(ws + 38404096);            // 2.5KB

  prep_kernel<<<8832, 256, 0, stream>>>(x, xb, Wq, bq, Wk, bk, Wv, bv, Wt, bias);
  proj_kernel<<<dim3(5, 128), 256, 0, stream>>>(xb, Wt, bias, qws, kp, vp);
  attn_ln_kernel<<<dim3(4, 128), 256, 0, stream>>>(qws, kp, vp, xb, gamma, beta, out);
}

// Round 17
// 122.867 us; speedup vs baseline: 1.4350x; 1.4350x over previous
//
#include <hip/hip_runtime.h>

#define NB 4
#define SEQ 4096
#define DM 512
#define DA 64
#define LOG2E 1.44269504f

typedef __attribute__((ext_vector_type(8))) short bf16x8;
typedef __attribute__((ext_vector_type(4))) float f32x4;
typedef __attribute__((ext_vector_type(16))) float f32x16;
typedef __attribute__((address_space(3))) unsigned int lds_u32;
typedef const __attribute__((address_space(1))) unsigned int glb_u32;

__device__ __forceinline__ unsigned short f2bf(float f) {
  unsigned u = __float_as_uint(f);
  u += 0x7fffu + ((u >> 16) & 1u);
  return (unsigned short)(u >> 16);
}

__device__ __forceinline__ float bf2f(unsigned short h) {
  return __uint_as_float(((unsigned)h) << 16);
}

__device__ __forceinline__ unsigned cvt_pk_bf16(float lo, float hi) {
  unsigned r;
  asm("v_cvt_pk_bf16_f32 %0, %1, %2" : "=v"(r) : "v"(lo), "v"(hi));
  return r;
}

__device__ __forceinline__ float fexp2(float x) {
  float r;
  asm("v_exp_f32 %0, %1" : "=v"(r) : "v"(x));
  return r;
}

__device__ __forceinline__ void g2lds16(const unsigned short* g, unsigned short* l) {
  __builtin_amdgcn_global_load_lds((glb_u32*)g, (lds_u32*)l, 16, 0, 0);
}

// ------------- Kernel 1: cast x -> bf16  AND  build Wt[640][512] + bias (merged) -----
__global__ void prep_kernel(const float* __restrict__ x, unsigned short* __restrict__ xb,
                            const float* __restrict__ Wq, const float* __restrict__ bq,
                            const float* __restrict__ Wk, const float* __restrict__ bk,
                            const float* __restrict__ Wv, const float* __restrict__ bv,
                            unsigned short* __restrict__ Wt, float* __restrict__ bias) {
  int bid = blockIdx.x;
  if (bid < 8192) {
    size_t i = ((size_t)bid * blockDim.x + threadIdx.x) * 4;
    float4 v = *(const float4*)(x + i);
    ushort4 o;
    o.x = f2bf(v.x); o.y = f2bf(v.y); o.z = f2bf(v.z); o.w = f2bf(v.w);
    *(ushort4*)(xb + i) = o;
  } else {
    int n = bid - 8192;  // 0..639
    for (int k = threadIdx.x; k < DM; k += blockDim.x) {
      float w;
      if (n < 64)       w = Wq[(size_t)k * DA + n];
      else if (n < 128) w = Wk[(size_t)k * DA + (n - 64)];
      else              w = Wv[(size_t)k * DM + (n - 128)];
      Wt[(size_t)n * DM + k] = f2bf(w);
    }
    if (threadIdx.x == 0)
      bias[n] = (n < 64) ? bq[n] : (n < 128) ? bk[n - 64] : bv[n - 128];
  }
}

// ------------- Kernel 2: projection GEMM, 128x128 tile, single-buffered LDS ----------
__launch_bounds__(256)
__global__ void proj_kernel(const unsigned short* __restrict__ xb,
                            const unsigned short* __restrict__ Wt,
                            const float* __restrict__ bias,
                            unsigned short* __restrict__ qws,
                            unsigned short* __restrict__ kp,
                            unsigned short* __restrict__ vp) {
  int C0 = blockIdx.x * 128;     // 0..512
  int R0 = blockIdx.y * 128;     // 0..16256
  int tid = threadIdx.x;
  int w = tid >> 6, lane = tid & 63;
  int g = (lane >> 4) & 3, c15 = lane & 15;
  int wr = w >> 1, wc = w & 1;

  __shared__ unsigned short smem[18432];   // A[8192] | B[8192] | epilogue overlap
  unsigned short* Ab = smem;
  unsigned short* Bb = smem + 8192;

  int row0 = tid >> 3;                     // 0..31
  int scol = (tid & 7) ^ (row0 & 7);       // pre-swizzled source slot
  const unsigned short* srcA = xb + (size_t)(R0 + row0) * DM + scol * 8;
  const unsigned short* srcB = Wt + (size_t)(C0 + row0) * DM + scol * 8;

  auto stage = [&](int kk) {
    for (int r = 0; r < 4; r++)
      g2lds16(srcA + (size_t)(r * 32) * DM + kk, &Ab[(r * 32 + w * 8) * 64]);
    for (int r = 0; r < 4; r++)
      g2lds16(srcB + (size_t)(r * 32) * DM + kk, &Bb[(r * 32 + w * 8) * 64]);
  };

  f32x4 acc[4][4];
#pragma unroll
  for (int i = 0; i < 4; i++)
#pragma unroll
    for (int j = 0; j < 4; j++) acc[i][j] = (f32x4)0.0f;

  stage(0);
  for (int s = 0; s < 8; s++) {
    __syncthreads();   // drain staging (vmcnt) before LDS reads
#pragma unroll
    for (int kc = 0; kc < 2; kc++) {
      bf16x8 a[4], bb2[4];
#pragma unroll
      for (int i = 0; i < 4; i++) {
        int row = wr * 64 + i * 16 + c15;
        a[i] = *(const bf16x8*)&Ab[row * 64 + (((kc << 2) | g) ^ (row & 7)) * 8];
      }
#pragma unroll
      for (int j = 0; j < 4; j++) {
        int row = wc * 64 + j * 16 + c15;
        bb2[j] = *(const bf16x8*)&Bb[row * 64 + (((kc << 2) | g) ^ (row & 7)) * 8];
      }
#pragma unroll
      for (int i = 0; i < 4; i++)
#pragma unroll
        for (int j = 0; j < 4; j++)
          acc[i][j] = __builtin_amdgcn_mfma_f32_16x16x32_bf16(a[i], bb2[j], acc[i][j], 0, 0, 0);
    }
    if (s < 7) {
      __syncthreads();   // all reads done before overwrite
      stage((s + 1) * 64);
    }
  }
  __syncthreads();       // protect epilogue smem reuse

  // ---- epilogue: per-wave 64x64 tile -> LDS [64][72] -> repacked coalesced stores ----
  unsigned short* tw = smem + w * 4608;
  int n0 = C0 + wc * 64;
#pragma unroll
  for (int j = 0; j < 4; j++) {
    int ncol = n0 + j * 16 + c15;
    float bv_ = bias[ncol];
    float qs = (ncol < 64) ? LOG2E : 1.0f;
#pragma unroll
    for (int i = 0; i < 4; i++)
#pragma unroll
      for (int r = 0; r < 4; r++) {
        int sl = i * 16 + g * 4 + r;
        tw[sl * 72 + j * 16 + c15] = f2bf((acc[i][j][r] + bv_) * qs);
      }
  }
  // wave-private region: compiler-inserted lgkmcnt orders write->read within the wave

  int RR = R0 + wr * 64;
  int b = RR >> 12, ktc = (RR & (SEQ - 1)) >> 6;
  if (n0 == 0) {
    for (int it = 0; it < 8; it++) {
      int rid = it * 64 + lane;
      int sl = rid >> 3, grp = rid & 7;
      bf16x8 vd = *(const bf16x8*)&tw[sl * 72 + grp * 8];
      *(bf16x8*)(qws + (size_t)(RR + sl) * DA + grp * 8) = vd;
    }
  } else if (n0 == 64) {
    for (int slot = 0; slot < 8; slot++) {
      bf16x8 vd = *(const bf16x8*)&tw[lane * 72 + slot * 8];
      *(bf16x8*)(kp + ((((size_t)b * 64 + ktc) * 8 + slot) * 64 + lane) * 8) = vd;
    }
  } else {
    int dvbase = n0 - 128;
    int dv = dvbase + lane;
    int dvc2 = dv >> 7, dvrow = dv & 127;
    for (int slot = 0; slot < 8; slot++) {
      union { unsigned short u[8]; bf16x8 h8; } pk;
#pragma unroll
      for (int j = 0; j < 8; j++) {
        int key = ((slot >> 2) << 5) | (((slot >> 1) & 1) << 4) | ((j >> 2) << 3) |
                  ((slot & 1) << 2) | (j & 3);
        pk.u[j] = tw[key * 72 + lane];
      }
      *(bf16x8*)(vp + (((((size_t)(b * 4 + dvc2)) * 64 + ktc) * 8 + slot) * 128 + dvrow) * 8) = pk.h8;
    }
  }
}

// ------------- Kernel 3: causal flash attention (proven 81.6us) ----------------------
// 32q/wave, dvc=4 split, split-K waves, no-max log2 softmax, L2-direct frags.
// launch_bounds(256,3): loop needs ~148 regs (84 VGPR + 64 AGPR). Do NOT request
// more waves (R14: spill, 2.5x slower) or fewer blocks (R16: concurrency collapse).
__launch_bounds__(256, 3)
__global__ void attn_kernel(const unsigned short* __restrict__ qws,
                            const unsigned short* __restrict__ kp,
                            const unsigned short* __restrict__ vp,
                            unsigned short* __restrict__ ob16) {
  int x = blockIdx.x, b = x >> 2, dvc = x & 3;
  int strip = 127 - blockIdx.y;
  int qrow32 = strip * 32;
  int n = (strip >> 1) + 1;
  int tid = threadIdx.x, w = tid >> 6, lane = tid & 63;
  int l31 = lane & 31, lh = lane >> 5;

  __shared__ unsigned short abuf[4][32][138];   // row stride 69 words, gcd(69,32)=1
  __shared__ float lbuf[4][32], Lfin[32];

  size_t bS = (size_t)b * SEQ;

  bf16x8 qf[4];
#pragma unroll
  for (int c = 0; c < 4; c++)
    qf[c] = *(const bf16x8*)(qws + (bS + qrow32 + l31) * DA + c * 16 + lh * 8);

  const unsigned short* kbase = kp + (size_t)b * 64 * 4096 + lh * 512 + l31 * 8;
  const unsigned short* vbase = vp + (size_t)(b * 4 + dvc) * 64 * 8192 + lh * 1024 + l31 * 8;

  f32x16 acc[4];
#pragma unroll
  for (int dt = 0; dt < 4; dt++) acc[dt] = (f32x16)0.0f;
  float la0 = 0.0f, la1 = 0.0f, la2 = 0.0f, la3 = 0.0f;

  for (int t = w; t < n; t += 4) {
    const unsigned short* kt_ = kbase + (size_t)t * 4096;
    const unsigned short* vt_ = vbase + (size_t)t * 8192;

    bf16x8 kf[4][2];
#pragma unroll
    for (int c = 0; c < 4; c++)
#pragma unroll
      for (int s2 = 0; s2 < 2; s2++)
        kf[c][s2] = *(const bf16x8*)(kt_ + c * 1024 + s2 * 256);
    bf16x8 vbA[4];
#pragma unroll
    for (int dt = 0; dt < 4; dt++)
      vbA[dt] = *(const bf16x8*)(vt_ + dt * 256);

    f32x16 sc[2];
    sc[0] = (f32x16)0.0f; sc[1] = (f32x16)0.0f;
    __builtin_amdgcn_s_setprio(1);
#pragma unroll
    for (int c = 0; c < 4; c++)
#pragma unroll
      for (int s2 = 0; s2 < 2; s2++)
        sc[s2] = __builtin_amdgcn_mfma_f32_32x32x16_bf16(kf[c][s2], qf[c], sc[s2], 0, 0, 0);
    __builtin_amdgcn_s_setprio(0);

    if (t == n - 1) {   // diagonal tile only (wave-uniform)
      int kt = t * 64, qrow = qrow32 + l31;
#pragma unroll
      for (int s2 = 0; s2 < 2; s2++)
#pragma unroll
        for (int p = 0; p < 16; p++) {
          int key = kt + s2 * 32 + (p & 3) + 8 * (p >> 2) + 4 * lh;
          if (key > qrow) sc[s2][p] = -1e30f;
        }
    }

    // ---- P = exp2(S) directly; accumulate l into 4 partials ----
#pragma unroll
    for (int s2 = 0; s2 < 2; s2++)
#pragma unroll
      for (int p = 0; p < 16; p += 4) {
        float p0 = fexp2(sc[s2][p + 0]);
        float p1 = fexp2(sc[s2][p + 1]);
        float p2 = fexp2(sc[s2][p + 2]);
        float p3 = fexp2(sc[s2][p + 3]);
        sc[s2][p + 0] = p0; sc[s2][p + 1] = p1;
        sc[s2][p + 2] = p2; sc[s2][p + 3] = p3;
        la0 += p0; la1 += p1; la2 += p2; la3 += p3;
      }

    bf16x8 pa[4];
#pragma unroll
    for (int c = 0; c < 4; c++) {
      union { unsigned u[4]; bf16x8 h; } pu;
      int s2 = c >> 1, o = (c & 1) * 8;
      pu.u[0] = cvt_pk_bf16(sc[s2][o + 0], sc[s2][o + 1]);
      pu.u[1] = cvt_pk_bf16(sc[s2][o + 2], sc[s2][o + 3]);
      pu.u[2] = cvt_pk_bf16(sc[s2][o + 4], sc[s2][o + 5]);
      pu.u[3] = cvt_pk_bf16(sc[s2][o + 6], sc[s2][o + 7]);
      pa[c] = pu.h;
    }

    __builtin_amdgcn_s_setprio(1);
#pragma unroll
    for (int c = 0; c < 4; c++) {
      bf16x8 vbB[4];
      if (c < 3) {
#pragma unroll
        for (int dt = 0; dt < 4; dt++)
          vbB[dt] = *(const bf16x8*)(vt_ + (c + 1) * 2048 + dt * 256);
      }
#pragma unroll
      for (int dt = 0; dt < 4; dt++)
        acc[dt] = __builtin_amdgcn_mfma_f32_32x32x16_bf16(vbA[dt], pa[c], acc[dt], 0, 0, 0);
      if (c < 3) {
#pragma unroll
        for (int dt = 0; dt < 4; dt++) vbA[dt] = vbB[dt];
      }
    }
    __builtin_amdgcn_s_setprio(0);
  }

  // ---- merge 4 waves' partials: plain sums ----
  float l_run = (la0 + la1) + (la2 + la3);
  l_run += __shfl_xor(l_run, 32);
  if (lh == 0) lbuf[w][l31] = l_run;
  __syncthreads();
  if (w == 0 && lh == 0)
    Lfin[l31] = lbuf[0][l31] + lbuf[1][l31] + lbuf[2][l31] + lbuf[3][l31];
#pragma unroll
  for (int dt = 0; dt < 4; dt++)
#pragma unroll
    for (int p = 0; p < 16; p += 2) {
      int dv = dt * 32 + (p & 3) + 8 * (p >> 2) + 4 * lh;
      *(unsigned*)&abuf[w][l31][dv] = cvt_pk_bf16(acc[dt][p], acc[dt][p + 1]);
    }
  __syncthreads();

  int q = w * 8 + (l31 >> 2);
  int ch = (l31 & 3) * 32 + lh * 16;
  float s[16];
#pragma unroll
  for (int k = 0; k < 16; k++) s[k] = 0.0f;
#pragma unroll
  for (int v = 0; v < 4; v++) {
    bf16x8 a0 = *(const bf16x8*)&abuf[v][q][ch];
    bf16x8 a1 = *(const bf16x8*)&abuf[v][q][ch + 8];
#pragma unroll
    for (int k = 0; k < 8; k++) {
      s[k] += bf2f((unsigned short)a0[k]);
      s[8 + k] += bf2f((unsigned short)a1[k]);
    }
  }
  float inv = 1.0f / Lfin[q];
  union { unsigned u[8]; bf16x8 h[2]; } o;
#pragma unroll
  for (int k = 0; k < 8; k++)
    o.u[k] = cvt_pk_bf16(s[2 * k] * inv, s[2 * k + 1] * inv);
  unsigned short* dst = ob16 + (bS + qrow32 + q) * DM + dvc * 128 + ch;
  *(bf16x8*)dst = o.h[0];
  *(bf16x8*)(dst + 8) = o.h[1];
}

// ------------- Kernel 4: residual + LayerNorm (bf16 x + bf16 o -> f32 out) ----------
__launch_bounds__(256)
__global__ void ln_kernel(const unsigned short* __restrict__ xb,
                          const unsigned short* __restrict__ o,
                          const float* __restrict__ gamma, const float* __restrict__ beta,
                          float* __restrict__ out) {
  int wid = threadIdx.x >> 6, lane = threadIdx.x & 63;
  size_t row = (size_t)blockIdx.x * 4 + wid;
  size_t base = row * DM + lane * 8;
  bf16x8 xv = *(const bf16x8*)(xb + base);
  bf16x8 ov = *(const bf16x8*)(o + base);
  float y[8];
#pragma unroll
  for (int j = 0; j < 8; j++)
    y[j] = bf2f((unsigned short)xv[j]) + bf2f((unsigned short)ov[j]);
  float s1 = 0.0f, s2 = 0.0f;
  for (int j = 0; j < 8; j++) { s1 += y[j]; s2 += y[j] * y[j]; }
  for (int m = 1; m < 64; m <<= 1) { s1 += __shfl_xor(s1, m); s2 += __shfl_xor(s2, m); }
  float mu = s1 * (1.0f / DM);
  float var = s2 * (1.0f / DM) - mu * mu;
  float rs = rsqrtf(var + 1e-5f);
  int c = lane * 8;
  for (int j = 0; j < 8; j++)
    out[base + j] = (y[j] - mu) * rs * gamma[c + j] + beta[c + j];
}

extern "C" void kernel_launch(void* const* d_in, const int* in_sizes, int n_in,
                              void* d_out, int out_size, void* d_ws, size_t ws_size,
                              hipStream_t stream) {
  const float* x     = (const float*)d_in[0];
  const float* Wq    = (const float*)d_in[1];
  const float* bq    = (const float*)d_in[2];
  const float* Wk    = (const float*)d_in[3];
  const float* bk    = (const float*)d_in[4];
  const float* Wv    = (const float*)d_in[5];
  const float* bv    = (const float*)d_in[6];
  const float* gamma = (const float*)d_in[7];
  const float* beta  = (const float*)d_in[8];
  float* out = (float*)d_out;

  char* ws = (char*)d_ws;
  unsigned short* xb   = (unsigned short*)(ws + 0);          // 16MB (alive through ln)
  unsigned short* qws  = (unsigned short*)(ws + 16777216);   // 2MB
  unsigned short* kp   = (unsigned short*)(ws + 18874368);   // 2MB
  unsigned short* vp   = (unsigned short*)(ws + 20971520);   // 16.78MB
  unsigned short* ob16 = (unsigned short*)(ws + 37748736);   // 16MB
  unsigned short* Wt   = (unsigned short*)(ws + 54525952);   // 0.66MB
  float*          bias = (float*)(ws + 55181312);            // 2.5KB

  prep_kernel<<<8832, 256, 0, stream>>>(x, xb, Wq, bq, Wk, bk, Wv, bv, Wt, bias);
  proj_kernel<<<dim3(5, 128), 256, 0, stream>>>(xb, Wt, bias, qws, kp, vp);
  attn_kernel<<<dim3(16, 128), 256, 0, stream>>>(qws, kp, vp, ob16);
  ln_kernel<<<4096, 256, 0, stream>>>(xb, ob16, gamma, beta, out);
}